// Round 9
// baseline (13366.376 us; speedup 1.0000x reference)
//
#include <hip/hip_runtime.h>

// Persistent-kernel Graves RNN, split-precision (bf16 hi/lo ~ fp32) recurrence.
// Round 9: halve the L3-coherent h-broadcast — 64 fat GEMM blocks x 8 h-cols
// (was 128 x 4). One set of h (B-operand) loads feeds 2 A-tiles (hcq=0,1), so
// per-block traffic is unchanged but total bypass traffic halves: 32->16 MB/step.
// A-frags: lo(m1,m2)+hi(m2) in LDS (120 KB, overlaid raw buffer); hi(m1) in
// per-unit VGPRs. K split across 2 wave-units as round 8. Barrier protocol,
// window path, numerics unchanged.
// Blocks [0,64): GEMM (8 h-cols). [64,128): window (1 batch row). 128: aggregator.

typedef unsigned int u32;
typedef unsigned short u16;
typedef unsigned long long u64;
typedef short short8 __attribute__((ext_vector_type(8)));
typedef float floatx4 __attribute__((ext_vector_type(4)));
typedef u32 u32x4 __attribute__((ext_vector_type(4)));

#define NBLK   129
#define NGEMM  64
#define AGG_BID 128
#define NTHR   512
#define SLEN   600

// workspace layout (bytes)
#define OFF_FLAG 0ull                          // u32 flags[NBLK] stride 16 u32
#define OFF_GEN  16384ull                      // u32 gen[8] stride 16 u32
#define OFF_H1P  32768ull                      // u32[64*512] packed (hi | lo<<16)
#define OFF_H2P  (OFF_H1P + 131072ull)
#define OFF_WP   (OFF_H2P + 131072ull)         // u32[64*96] packed (cols 80..95 zero)
#define OFF_XHI  (OFF_WP + 24576ull)           // u16[600*64*32]
#define OFF_XLO  (OFF_XHI + 2457600ull)
#define OFF_HS2  (OFF_XLO + 2457600ull)        // u16[64*600*512] (plain cached)
#define WS_NEED  (OFF_HS2 + 39321600ull)       // ~44.6 MB

// LDS raw-buffer offsets (bytes). GEMM role:
//   LO(m,ks,hcq):  lo A-frags, m=0 LSTM1 / m=1 LSTM2, ks 0..19, hcq 0..1
//   HI2(ks,hcq):   hi A-frags for LSTM2
//   PLDS(m,hcq):   unit0 partial gates (256 lanes x 16 B)
// Window role overlays the LO region (different blocks).
#define L_LO(m,ks,hcq)  ((((m)*20+(ks))*2+(hcq)) << 10)
#define L_HI2(ks,hcq)   (81920u + ((((ks)*2+(hcq))) << 10))
#define L_PLDS(m,hcq)   (122880u + (((m)*2+(hcq)) << 12))
#define LDS_BYTES 139264u

__device__ __forceinline__ float bf2f(short h) {
  return __uint_as_float(((u32)(u16)h) << 16);
}
__device__ __forceinline__ u16 f2bf(float f) {          // RNE
  u32 u = __float_as_uint(f);
  u += 0x7fffu + ((u >> 16) & 1u);
  return (u16)(u >> 16);
}
__device__ __forceinline__ float fsig(float x) { return 1.0f / (1.0f + __expf(-x)); }
__device__ __forceinline__ float ftanh_(float x) { return 2.0f / (1.0f + __expf(-2.0f * x)) - 1.0f; }

__device__ __forceinline__ float lstm_point(floatx4 g, float& c) {
  float i  = fsig(g[0]);
  float f  = fsig(g[1]);
  float gg = ftanh_(g[2]);
  float o  = fsig(g[3]);
  c = f * c + i * gg;
  return o * ftanh_(c);
}

// pack v as (trunc-bf16 hi) | (RNE-bf16 of remainder << 16)
__device__ __forceinline__ u32 pack_split(float v) {
  u32 b = __float_as_uint(v);
  float rem = v - __uint_as_float(b & 0xffff0000u);
  return (b >> 16) | ((u32)f2bf(rem) << 16);
}

// coherent (agent-scope, L2-bypass) helpers
__device__ __forceinline__ void st_coh(u32* p, u32 v) {
  __hip_atomic_store(p, v, __ATOMIC_RELAXED, __HIP_MEMORY_SCOPE_AGENT);
}
__device__ __forceinline__ u32 ld_coh(const u32* p) {
  return __hip_atomic_load((u32*)p, __ATOMIC_RELAXED, __HIP_MEMORY_SCOPE_AGENT);
}

// load 8 consecutive packed u32 (coherent), split into hi/lo bf16 short8
__device__ __forceinline__ void ld_pk8(const u32* p, short8& hi, short8& lo) {
  u64 d0 = __hip_atomic_load((u64*)(p + 0), __ATOMIC_RELAXED, __HIP_MEMORY_SCOPE_AGENT);
  u64 d1 = __hip_atomic_load((u64*)(p + 2), __ATOMIC_RELAXED, __HIP_MEMORY_SCOPE_AGENT);
  u64 d2 = __hip_atomic_load((u64*)(p + 4), __ATOMIC_RELAXED, __HIP_MEMORY_SCOPE_AGENT);
  u64 d3 = __hip_atomic_load((u64*)(p + 6), __ATOMIC_RELAXED, __HIP_MEMORY_SCOPE_AGENT);
  u32 a0 = (u32)d0, a1 = (u32)(d0 >> 32), a2 = (u32)d1, a3 = (u32)(d1 >> 32);
  u32 a4 = (u32)d2, a5 = (u32)(d2 >> 32), a6 = (u32)d3, a7 = (u32)(d3 >> 32);
  u32x4 h, l;
  h[0] = __builtin_amdgcn_perm(a1, a0, 0x05040100u); l[0] = __builtin_amdgcn_perm(a1, a0, 0x07060302u);
  h[1] = __builtin_amdgcn_perm(a3, a2, 0x05040100u); l[1] = __builtin_amdgcn_perm(a3, a2, 0x07060302u);
  h[2] = __builtin_amdgcn_perm(a5, a4, 0x05040100u); l[2] = __builtin_amdgcn_perm(a5, a4, 0x07060302u);
  h[3] = __builtin_amdgcn_perm(a7, a6, 0x05040100u); l[3] = __builtin_amdgcn_perm(a7, a6, 0x07060302u);
  hi = __builtin_bit_cast(short8, h);
  lo = __builtin_bit_cast(short8, l);
}

// ---- 2-hop aggregator barrier ----
__device__ __forceinline__ void sync_wait(u32* flags, u32* gen, u32 lgen, int bid) {
  if (bid == AGG_BID) {
    const int i = threadIdx.x;
    if (i < NBLK) {
      u32 sp = 0;
      while (ld_coh(&flags[i * 16]) < lgen) {
        __builtin_amdgcn_s_sleep(1);
        if (++sp > (1u << 22)) break;   // safety valve
      }
    }
    __syncthreads();
    if (threadIdx.x < 8) st_coh(&gen[threadIdx.x * 16], lgen);
  } else {
    if (threadIdx.x == 0) {
      u32 sp = 0;
      while (ld_coh(&gen[(bid & 7) * 16]) < lgen) {
        __builtin_amdgcn_s_sleep(2);
        if (++sp > (1u << 22)) break;   // safety valve
      }
    }
  }
}

// light barrier: no cache maintenance (mutable shared data uses coherent ops)
__device__ __forceinline__ void sync_light(u32* flags, u32* gen, u32& lgen, int bid) {
  asm volatile("s_waitcnt vmcnt(0) lgkmcnt(0)" ::: "memory");  // drain own stores
  __syncthreads();
  lgen++;
  if (threadIdx.x == 0) st_coh(&flags[bid * 16], lgen);
  sync_wait(flags, gen, lgen, bid);
  __syncthreads();
  asm volatile("" ::: "memory");
}

// full barrier: with L2 writeback/invalidate (prologue + pre-epilogue only)
__device__ __forceinline__ void sync_full(u32* flags, u32* gen, u32& lgen, int bid) {
  __syncthreads();
  lgen++;
  if (threadIdx.x == 0) {
    __threadfence();                 // release: wb dirty L2 (xpad / hs2)
    st_coh(&flags[bid * 16], lgen);
  }
  sync_wait(flags, gen, lgen, bid);
  if (threadIdx.x == 0) __threadfence();   // acquire: invalidate
  __syncthreads();
  asm volatile("" ::: "memory");
}

__global__ void init_ws(unsigned char* ws) {
  const int gtid = blockIdx.x * 256 + threadIdx.x;
  u32* flg = (u32*)(ws + OFF_FLAG);
  for (int i = gtid; i < NBLK * 16; i += 64 * 256) flg[i] = 0u;
  u32* gn = (u32*)(ws + OFF_GEN);
  if (gtid < 128) gn[gtid] = 0u;
  u32* h2p = (u32*)(ws + OFF_H2P);
  for (int i = gtid; i < 64 * 512; i += 64 * 256) h2p[i] = 0u;   // h2_{-1}=0
  u32* wp = (u32*)(ws + OFF_WP);
  for (int i = gtid; i < 64 * 96; i += 64 * 256) wp[i] = 0u;     // w pad cols
}

__global__ __launch_bounds__(NTHR, 1) void rnn_kernel(
    const float* __restrict__ x, const float* __restrict__ chars,
    const float* __restrict__ Wih1, const float* __restrict__ Whh1,
    const float* __restrict__ bih1, const float* __restrict__ bhh1,
    const float* __restrict__ Wwin, const float* __restrict__ bwin,
    const float* __restrict__ Wih2, const float* __restrict__ Whh2,
    const float* __restrict__ bih2, const float* __restrict__ bhh2,
    const float* __restrict__ Wmdn, const float* __restrict__ bmdn,
    float* __restrict__ out, unsigned char* __restrict__ ws)
{
  const int bid = blockIdx.x;
  const int tid = threadIdx.x;
  const int wid = tid >> 6;
  const int lane = tid & 63;
  const int unit = wid >> 2;        // 0: waves 0-3, 1: waves 4-7

  u32* flags = (u32*)(ws + OFF_FLAG);
  u32* gen   = (u32*)(ws + OFF_GEN);
  u32* h1p   = (u32*)(ws + OFF_H1P);
  u32* h2p   = (u32*)(ws + OFF_H2P);
  u32* wp    = (u32*)(ws + OFF_WP);
  u16* xhi   = (u16*)(ws + OFF_XHI);
  u16* xlo   = (u16*)(ws + OFF_XLO);
  u16* hs2   = (u16*)(ws + OFF_HS2);

  u32 lgen = 0;

  __shared__ __align__(16) unsigned char lds_raw[LDS_BYTES];
  // window-role overlay pointers
  float* chars_s = (float*)lds_raw;                 // 64*80*4 = 20480
  float* smem_f  = (float*)(lds_raw + 20480);       // 512*4   =  2048
  float* wout_s  = (float*)(lds_raw + 22528);       // 64*4
  float* al_s    = (float*)(lds_raw + 22784);       // 20*4
  float* be_s    = (float*)(lds_raw + 22864);
  float* kp_s    = (float*)(lds_raw + 22944);

  // ---- prologue: split x into xhi/xlo [t][b][32] (plain stores; full barrier) ----
  for (int i = bid * NTHR + tid; i < SLEN * 64 * 32; i += NBLK * NTHR) {
    int t = i >> 11;
    int r = i & 2047;
    int bb = r >> 5, q = r & 31;
    float v = (q < 3) ? x[((size_t)bb * SLEN + t) * 3 + q] : 0.0f;
    u32 b = __float_as_uint(v);
    xhi[i] = (u16)(b >> 16);
    xlo[i] = f2bf(v - __uint_as_float(b & 0xffff0000u));
  }

  const bool isg = (bid < NGEMM);
  const bool isw = (bid >= NGEMM && bid < NGEMM + 64);

  // hi A-frags for LSTM1, per-unit K-slots (VGPR):
  //   unit0 slot s: ks = s (s<8) or 19 (s==8); unit1 slot s: ks = 8+s (s 0..10)
  short8 af1h[2][11];
  floatx4 bs1q[2] = {{0,0,0,0},{0,0,0,0}}, bs2q[2] = {{0,0,0,0},{0,0,0,0}};
  float c1q[2] = {0.0f, 0.0f}, c2q[2] = {0.0f, 0.0f};
  int b_row = 0;
  int hcv[2] = {0, 0};
  float bw = 0.0f;
  const int kg = (lane >> 4) * 8;

  if (isg) {
    b_row = 16 * (wid & 3) + (lane & 15);
    hcv[0] = 8 * bid + (lane >> 4);
    hcv[1] = 8 * bid + 4 + (lane >> 4);
    const int ra = lane & 15;
    // wave 0: build LDS frags (lo m1/m2, hi m2) for both hcq
    if (wid == 0) {
      #pragma unroll
      for (int hcq = 0; hcq < 2; ++hcq) {
        const int origA = (ra & 3) * 512 + 8 * bid + 4 * hcq + (ra >> 2);
        #pragma unroll
        for (int ks = 0; ks < 20; ++ks) {
          short8 v1l, v2h, v2l;
          #pragma unroll
          for (int j = 0; j < 8; ++j) {
            int k = 32 * ks + kg + j;
            float a1 = 0.0f, a2 = 0.0f;
            if (k < 512) {
              a1 = Whh1[(size_t)origA * 512 + k];
              a2 = Whh2[(size_t)origA * 512 + k];
            } else if (k < 592) {
              a1 = Wih1[(size_t)origA * 83 + 3 + (k - 512)];
              a2 = Wih2[(size_t)origA * 83 + 3 + (k - 512)];
            } else if (k >= 608 && k < 611) {
              a1 = Wih1[(size_t)origA * 83 + (k - 608)];
              a2 = Wih2[(size_t)origA * 83 + (k - 608)];
            }
            u32 b1 = __float_as_uint(a1), b2 = __float_as_uint(a2);
            v2h[j] = (short)(u16)(b2 >> 16);
            v1l[j] = (short)f2bf(a1 - __uint_as_float(b1 & 0xffff0000u));
            v2l[j] = (short)f2bf(a2 - __uint_as_float(b2 & 0xffff0000u));
          }
          *(short8*)(lds_raw + L_HI2(ks, hcq) + (lane << 4)) = v2h;
          *(short8*)(lds_raw + L_LO(0, ks, hcq) + (lane << 4)) = v1l;
          *(short8*)(lds_raw + L_LO(1, ks, hcq) + (lane << 4)) = v2l;
        }
      }
    }
    // every thread: build its unit's hi-m1 VGPR frags
    #pragma unroll
    for (int hcq = 0; hcq < 2; ++hcq) {
      const int origA = (ra & 3) * 512 + 8 * bid + 4 * hcq + (ra >> 2);
      #pragma unroll
      for (int s = 0; s < 11; ++s) {
        int ks = (unit == 0) ? ((s < 8) ? s : 19) : (8 + s);
        short8 vh;
        #pragma unroll
        for (int j = 0; j < 8; ++j) {
          int k = 32 * ks + kg + j;
          float a1 = 0.0f;
          if (k < 512)                    a1 = Whh1[(size_t)origA * 512 + k];
          else if (k < 592)               a1 = Wih1[(size_t)origA * 83 + 3 + (k - 512)];
          else if (k >= 608 && k < 611)   a1 = Wih1[(size_t)origA * 83 + (k - 608)];
          vh[j] = (short)(u16)(__float_as_uint(a1) >> 16);
        }
        af1h[hcq][s] = vh;
      }
    }
    #pragma unroll
    for (int hcq = 0; hcq < 2; ++hcq)
      #pragma unroll
      for (int r = 0; r < 4; ++r) {
        bs1q[hcq][r] = bih1[r * 512 + hcv[hcq]] + bhh1[r * 512 + hcv[hcq]];
        bs2q[hcq][r] = bih2[r * 512 + hcv[hcq]] + bhh2[r * 512 + hcv[hcq]];
      }
  } else if (isw) {
    const int b = bid - NGEMM;
    for (int i = tid; i < 64 * 80; i += NTHR)
      chars_s[i] = chars[(size_t)b * 5120 + i];
    if (tid < 20) kp_s[tid] = 0.0f;
    if (tid < 60) bw = bwin[tid];
  }

  sync_full(flags, gen, lgen, bid);   // xpad visible, LDS frags ready

  // ---- phase 0: h1_0 = lstm(b1 + x_0*Wx1); unit0 computes, unit1 publishes ----
  if (isg) {
    if (unit == 0) {
      short8 xh = *(const short8*)(xhi + (size_t)b_row * 32 + kg);
      short8 xl = *(const short8*)(xlo + (size_t)b_row * 32 + kg);
      #pragma unroll
      for (int hcq = 0; hcq < 2; ++hcq) {
        floatx4 a = {0.f,0.f,0.f,0.f}, b = a, c = a;
        short8 ah = af1h[hcq][8];   // ks 19
        short8 al = *(const short8*)(lds_raw + L_LO(0, 19, hcq) + (lane << 4));
        a = __builtin_amdgcn_mfma_f32_16x16x32_bf16(ah, xh, a, 0, 0, 0);
        b = __builtin_amdgcn_mfma_f32_16x16x32_bf16(ah, xl, b, 0, 0, 0);
        c = __builtin_amdgcn_mfma_f32_16x16x32_bf16(al, xh, c, 0, 0, 0);
        *(floatx4*)(lds_raw + L_PLDS(0, hcq) + (tid << 4)) = a + b + c;
      }
    }
    __syncthreads();
    if (unit == 1) {
      const int j = tid & 255;
      #pragma unroll
      for (int hcq = 0; hcq < 2; ++hcq) {
        floatx4 g = *(const floatx4*)(lds_raw + L_PLDS(0, hcq) + (j << 4)) + bs1q[hcq];
        float h = lstm_point(g, c1q[hcq]);
        st_coh(&h1p[b_row * 512 + hcv[hcq]], pack_split(h));
      }
    }
  }

  sync_light(flags, gen, lgen, bid);   // h1_0 visible

  // ---- main loop ----
  for (int t = 0; t < SLEN; ++t) {
    floatx4 a1[2][3], a2[2][3];
    #pragma unroll
    for (int hcq = 0; hcq < 2; ++hcq)
      #pragma unroll
      for (int m = 0; m < 3; ++m) { a1[hcq][m] = {0.f,0.f,0.f,0.f}; a2[hcq][m] = {0.f,0.f,0.f,0.f}; }

    // ======== phase A ========
    if (isg) {
      if (unit == 0) {
        // LSTM2 partial: h2 ks0-7 + x(t)  -> PLDS(1,·)
        {
          short8 bh[8], bl[8];
          #pragma unroll
          for (int k = 0; k < 8; ++k)
            ld_pk8(h2p + b_row * 512 + k * 32 + kg, bh[k], bl[k]);
          #pragma unroll
          for (int k = 0; k < 8; ++k)
            #pragma unroll
            for (int hcq = 0; hcq < 2; ++hcq) {
              short8 ah = *(const short8*)(lds_raw + L_HI2(k, hcq) + (lane << 4));
              short8 al = *(const short8*)(lds_raw + L_LO(1, k, hcq) + (lane << 4));
              a2[hcq][0] = __builtin_amdgcn_mfma_f32_16x16x32_bf16(ah, bh[k], a2[hcq][0], 0, 0, 0);
              a2[hcq][1] = __builtin_amdgcn_mfma_f32_16x16x32_bf16(ah, bl[k], a2[hcq][1], 0, 0, 0);
              a2[hcq][2] = __builtin_amdgcn_mfma_f32_16x16x32_bf16(al, bh[k], a2[hcq][2], 0, 0, 0);
            }
          short8 xh = *(const short8*)(xhi + ((size_t)t * 64 + b_row) * 32 + kg);
          short8 xl = *(const short8*)(xlo + ((size_t)t * 64 + b_row) * 32 + kg);
          #pragma unroll
          for (int hcq = 0; hcq < 2; ++hcq) {
            short8 ah = *(const short8*)(lds_raw + L_HI2(19, hcq) + (lane << 4));
            short8 al = *(const short8*)(lds_raw + L_LO(1, 19, hcq) + (lane << 4));
            a2[hcq][0] = __builtin_amdgcn_mfma_f32_16x16x32_bf16(ah, xh, a2[hcq][0], 0, 0, 0);
            a2[hcq][1] = __builtin_amdgcn_mfma_f32_16x16x32_bf16(ah, xl, a2[hcq][1], 0, 0, 0);
            a2[hcq][2] = __builtin_amdgcn_mfma_f32_16x16x32_bf16(al, xh, a2[hcq][2], 0, 0, 0);
            *(floatx4*)(lds_raw + L_PLDS(1, hcq) + (tid << 4)) = a2[hcq][0] + a2[hcq][1] + a2[hcq][2];
          }
        }
        // LSTM1 partial: h1 ks0-7 + x(t+1) -> PLDS(0,·)
        if (t < SLEN - 1) {
          short8 bh[8], bl[8];
          #pragma unroll
          for (int k = 0; k < 8; ++k)
            ld_pk8(h1p + b_row * 512 + k * 32 + kg, bh[k], bl[k]);
          #pragma unroll
          for (int k = 0; k < 8; ++k)
            #pragma unroll
            for (int hcq = 0; hcq < 2; ++hcq) {
              short8 ah = af1h[hcq][k];
              short8 al = *(const short8*)(lds_raw + L_LO(0, k, hcq) + (lane << 4));
              a1[hcq][0] = __builtin_amdgcn_mfma_f32_16x16x32_bf16(ah, bh[k], a1[hcq][0], 0, 0, 0);
              a1[hcq][1] = __builtin_amdgcn_mfma_f32_16x16x32_bf16(ah, bl[k], a1[hcq][1], 0, 0, 0);
              a1[hcq][2] = __builtin_amdgcn_mfma_f32_16x16x32_bf16(al, bh[k], a1[hcq][2], 0, 0, 0);
            }
          short8 xh = *(const short8*)(xhi + ((size_t)(t + 1) * 64 + b_row) * 32 + kg);
          short8 xl = *(const short8*)(xlo + ((size_t)(t + 1) * 64 + b_row) * 32 + kg);
          #pragma unroll
          for (int hcq = 0; hcq < 2; ++hcq) {
            short8 ah = af1h[hcq][8];   // ks 19
            short8 al = *(const short8*)(lds_raw + L_LO(0, 19, hcq) + (lane << 4));
            a1[hcq][0] = __builtin_amdgcn_mfma_f32_16x16x32_bf16(ah, xh, a1[hcq][0], 0, 0, 0);
            a1[hcq][1] = __builtin_amdgcn_mfma_f32_16x16x32_bf16(ah, xl, a1[hcq][1], 0, 0, 0);
            a1[hcq][2] = __builtin_amdgcn_mfma_f32_16x16x32_bf16(al, xh, a1[hcq][2], 0, 0, 0);
            *(floatx4*)(lds_raw + L_PLDS(0, hcq) + (tid << 4)) = a1[hcq][0] + a1[hcq][1] + a1[hcq][2];
          }
        }
      } else {
        // unit 1: LSTM2 h2 ks8-15 (accumulators live into phase B)
        {
          short8 bh[8], bl[8];
          #pragma unroll
          for (int k = 0; k < 8; ++k)
            ld_pk8(h2p + b_row * 512 + (8 + k) * 32 + kg, bh[k], bl[k]);
          #pragma unroll
          for (int k = 0; k < 8; ++k)
            #pragma unroll
            for (int hcq = 0; hcq < 2; ++hcq) {
              short8 ah = *(const short8*)(lds_raw + L_HI2(8 + k, hcq) + (lane << 4));
              short8 al = *(const short8*)(lds_raw + L_LO(1, 8 + k, hcq) + (lane << 4));
              a2[hcq][0] = __builtin_amdgcn_mfma_f32_16x16x32_bf16(ah, bh[k], a2[hcq][0], 0, 0, 0);
              a2[hcq][1] = __builtin_amdgcn_mfma_f32_16x16x32_bf16(ah, bl[k], a2[hcq][1], 0, 0, 0);
              a2[hcq][2] = __builtin_amdgcn_mfma_f32_16x16x32_bf16(al, bh[k], a2[hcq][2], 0, 0, 0);
            }
        }
        // LSTM1 h1 ks8-15
        if (t < SLEN - 1) {
          short8 bh[8], bl[8];
          #pragma unroll
          for (int k = 0; k < 8; ++k)
            ld_pk8(h1p + b_row * 512 + (8 + k) * 32 + kg, bh[k], bl[k]);
          #pragma unroll
          for (int k = 0; k < 8; ++k)
            #pragma unroll
            for (int hcq = 0; hcq < 2; ++hcq) {
              short8 ah = af1h[hcq][k];   // ks 8+k
              short8 al = *(const short8*)(lds_raw + L_LO(0, 8 + k, hcq) + (lane << 4));
              a1[hcq][0] = __builtin_amdgcn_mfma_f32_16x16x32_bf16(ah, bh[k], a1[hcq][0], 0, 0, 0);
              a1[hcq][1] = __builtin_amdgcn_mfma_f32_16x16x32_bf16(ah, bl[k], a1[hcq][1], 0, 0, 0);
              a1[hcq][2] = __builtin_amdgcn_mfma_f32_16x16x32_bf16(al, bh[k], a1[hcq][2], 0, 0, 0);
            }
        }
      }
    } else if (isw) {
      // ---- window block b: w(t) from h1(t), fp32, 8 K-groups ----
      const int b = bid - NGEMM;
      {
        u32 p = ld_coh(&h1p[b * 512 + tid]);
        smem_f[tid] = bf2f((short)(u16)p) + bf2f((short)(u16)(p >> 16));
      }
      __syncthreads();
      const int col = tid & 63;
      const int kq  = tid >> 6;          // 0..7, 64 K each
      float p = 0.0f;
      if (col < 60) {
        const floatx4* wr = (const floatx4*)(Wwin + (size_t)col * 512 + kq * 64);
        const floatx4* hr = (const floatx4*)(smem_f + kq * 64);
        #pragma unroll
        for (int k4 = 0; k4 < 16; ++k4) {
          floatx4 wv = wr[k4];
          floatx4 hv = hr[k4];
          p = fmaf(wv[0], hv[0], p);
          p = fmaf(wv[1], hv[1], p);
          p = fmaf(wv[2], hv[2], p);
          p = fmaf(wv[3], hv[3], p);
        }
      }
      __syncthreads();
      smem_f[tid] = p;
      __syncthreads();
      if (tid < 60) {
        float s = 0.0f;
        #pragma unroll
        for (int q = 0; q < 8; ++q) s += smem_f[q * 64 + tid];
        wout_s[tid] = s + bw;
      }
      __syncthreads();
      if (tid < 20) {
        al_s[tid] = __expf(wout_s[tid]);
        be_s[tid] = __expf(wout_s[20 + tid]);
        kp_s[tid] += __expf(wout_s[40 + tid]);
      }
      __syncthreads();
      if (tid < 64) {
        float u = (float)tid;
        float ph = 0.0f;
        #pragma unroll
        for (int k = 0; k < 20; ++k) {
          float d = kp_s[k] - u;
          ph = fmaf(al_s[k], __expf(-be_s[k] * d * d), ph);
        }
        smem_f[tid] = ph;
      }
      __syncthreads();
      if (tid < 80) {
        float wv = 0.0f;
        for (int u = 0; u < 64; ++u)
          wv = fmaf(smem_f[u], chars_s[u * 80 + tid], wv);
        st_coh(&wp[b * 96 + tid], pack_split(wv));
      }
    }

    sync_light(flags, gen, lgen, bid);   // w(t) visible; unit0 partials in LDS

    // ======== phase B (unit 1 only) ========
    if (isg && unit == 1) {
      const int j = tid & 255;
      short8 wh[3], wl[3];
      ld_pk8(wp + b_row * 96 +  0 + kg, wh[0], wl[0]);
      ld_pk8(wp + b_row * 96 + 32 + kg, wh[1], wl[1]);
      ld_pk8(wp + b_row * 96 + 64 + kg, wh[2], wl[2]);
      #pragma unroll
      for (int jj = 0; jj < 3; ++jj)
        #pragma unroll
        for (int hcq = 0; hcq < 2; ++hcq) {
          short8 ah = *(const short8*)(lds_raw + L_HI2(16 + jj, hcq) + (lane << 4));
          short8 al = *(const short8*)(lds_raw + L_LO(1, 16 + jj, hcq) + (lane << 4));
          a2[hcq][0] = __builtin_amdgcn_mfma_f32_16x16x32_bf16(ah, wh[jj], a2[hcq][0], 0, 0, 0);
          a2[hcq][1] = __builtin_amdgcn_mfma_f32_16x16x32_bf16(ah, wl[jj], a2[hcq][1], 0, 0, 0);
          a2[hcq][2] = __builtin_amdgcn_mfma_f32_16x16x32_bf16(al, wh[jj], a2[hcq][2], 0, 0, 0);
        }
      #pragma unroll
      for (int hcq = 0; hcq < 2; ++hcq) {
        floatx4 g2 = a2[hcq][0] + a2[hcq][1] + a2[hcq][2]
                   + *(const floatx4*)(lds_raw + L_PLDS(1, hcq) + (j << 4)) + bs2q[hcq];
        float h2v = lstm_point(g2, c2q[hcq]);
        st_coh(&h2p[b_row * 512 + hcv[hcq]], pack_split(h2v));
        hs2[((size_t)b_row * SLEN + t) * 512 + hcv[hcq]] = f2bf(h2v);   // plain cached
      }
      if (t < SLEN - 1) {
        #pragma unroll
        for (int jj = 0; jj < 3; ++jj)
          #pragma unroll
          for (int hcq = 0; hcq < 2; ++hcq) {
            short8 ah = af1h[hcq][8 + jj];   // ks 16+jj
            short8 al = *(const short8*)(lds_raw + L_LO(0, 16 + jj, hcq) + (lane << 4));
            a1[hcq][0] = __builtin_amdgcn_mfma_f32_16x16x32_bf16(ah, wh[jj], a1[hcq][0], 0, 0, 0);
            a1[hcq][1] = __builtin_amdgcn_mfma_f32_16x16x32_bf16(ah, wl[jj], a1[hcq][1], 0, 0, 0);
            a1[hcq][2] = __builtin_amdgcn_mfma_f32_16x16x32_bf16(al, wh[jj], a1[hcq][2], 0, 0, 0);
          }
        #pragma unroll
        for (int hcq = 0; hcq < 2; ++hcq) {
          floatx4 g1 = a1[hcq][0] + a1[hcq][1] + a1[hcq][2]
                     + *(const floatx4*)(lds_raw + L_PLDS(0, hcq) + (j << 4)) + bs1q[hcq];
          float h1v = lstm_point(g1, c1q[hcq]);
          st_coh(&h1p[b_row * 512 + hcv[hcq]], pack_split(h1v));
        }
      }
    }

    sync_light(flags, gen, lgen, bid);   // h1(t+1), h2(t) visible
  }

  sync_full(flags, gen, lgen, bid);   // flush hs2 to L3 before epilogue

  // ---- epilogue: MDN head, one row per thread ----
  {
    const int row = bid * NTHR + tid;          // row = b*600 + t
    if (row < 38400) {
      const u16* hrow = hs2 + (size_t)row * 512;
      {
        float acc = bmdn[0];
        for (int k8 = 0; k8 < 512; k8 += 8) {
          short8 hv = *(const short8*)(hrow + k8);
          #pragma unroll
          for (int j = 0; j < 8; ++j) acc = fmaf(bf2f(hv[j]), Wmdn[k8 + j], acc);
        }
        out[row] = fsig(acc);
      }
      {
        float a[20];
        #pragma unroll
        for (int cc = 0; cc < 20; ++cc) a[cc] = bmdn[1 + cc];
        for (int k8 = 0; k8 < 512; k8 += 8) {
          short8 hv = *(const short8*)(hrow + k8);
          float hf[8];
          #pragma unroll
          for (int j = 0; j < 8; ++j) hf[j] = bf2f(hv[j]);
          #pragma unroll
          for (int cc = 0; cc < 20; ++cc) {
            const float* wr = Wmdn + (size_t)(1 + cc) * 512 + k8;
            #pragma unroll
            for (int j = 0; j < 8; ++j) a[cc] = fmaf(hf[j], wr[j], a[cc]);
          }
        }
        float mx = a[0];
        #pragma unroll
        for (int cc = 1; cc < 20; ++cc) mx = fmaxf(mx, a[cc]);
        float s = 0.0f;
        #pragma unroll
        for (int cc = 0; cc < 20; ++cc) { a[cc] = __expf(a[cc] - mx); s += a[cc]; }
        float inv = 1.0f / s;
        float* po = out + 38400 + (size_t)row * 20;
        #pragma unroll
        for (int cc = 0; cc < 20; ++cc) po[cc] = a[cc] * inv;
      }
      for (int grp = 1; grp <= 5; ++grp) {
        float a[20];
        #pragma unroll
        for (int cc = 0; cc < 20; ++cc) a[cc] = bmdn[1 + 20 * grp + cc];
        for (int k8 = 0; k8 < 512; k8 += 8) {
          short8 hv = *(const short8*)(hrow + k8);
          float hf[8];
          #pragma unroll
          for (int j = 0; j < 8; ++j) hf[j] = bf2f(hv[j]);
          #pragma unroll
          for (int cc = 0; cc < 20; ++cc) {
            const float* wr = Wmdn + (size_t)(1 + 20 * grp + cc) * 512 + k8;
            #pragma unroll
            for (int j = 0; j < 8; ++j) a[cc] = fmaf(hf[j], wr[j], a[cc]);
          }
        }
        float* po = out + 38400 + (size_t)grp * 768000 + (size_t)row * 20;
        if (grp == 3 || grp == 4) {
          #pragma unroll
          for (int cc = 0; cc < 20; ++cc) po[cc] = __expf(a[cc]);
        } else if (grp == 5) {
          #pragma unroll
          for (int cc = 0; cc < 20; ++cc) po[cc] = ftanh_(a[cc]);
        } else {
          #pragma unroll
          for (int cc = 0; cc < 20; ++cc) po[cc] = a[cc];
        }
      }
    }
  }
}

extern "C" void kernel_launch(void* const* d_in, const int* in_sizes, int n_in,
                              void* d_out, int out_size, void* d_ws, size_t ws_size,
                              hipStream_t stream) {
  (void)in_sizes; (void)n_in; (void)out_size;
  if (ws_size < WS_NEED) return;   // need ~44.6 MB scratch
  init_ws<<<dim3(64), dim3(256), 0, stream>>>((unsigned char*)d_ws);
  rnn_kernel<<<dim3(NBLK), dim3(NTHR), 0, stream>>>(
      (const float*)d_in[0],  (const float*)d_in[1],
      (const float*)d_in[2],  (const float*)d_in[3],
      (const float*)d_in[4],  (const float*)d_in[5],
      (const float*)d_in[6],  (const float*)d_in[7],
      (const float*)d_in[8],  (const float*)d_in[9],
      (const float*)d_in[10], (const float*)d_in[11],
      (const float*)d_in[12], (const float*)d_in[13],
      (float*)d_out, (unsigned char*)d_ws);
}